// Round 1
// baseline (101.765 us; speedup 1.0000x reference)
//
#include <hip/hip_runtime.h>
#include <hip/hip_bf16.h>

// EmbeddingPredictor: B=16 T=2048 V=32000 E=512 H=4 C=3, f32 in/out.
// R1 design:
//  K0 prep:  P[c][e] = sum_h pos[h,e,c]  (multi-head collapses algebraically);
//            Wb = bf16(ffn_w)
//  K1 ctx:   per token t: s[c] = dot(x_c, P[:,c]); out1 = sum_c s[c]*x_c /12 -> bf16
//  K2 ffn:   MFMA bf16 GEMM y = out1 @ W^T + b, fused LayerNorm + swish -> f32 out
// ws: Pt @0 (6KB), Wb @8KB (512KB), out1 @1MB (33.5MB). Total ~34.6MB.

#define Bq 16
#define Tq 2048
#define Eq 512
#define Cq 3
#define Hq 4
#define Mq (Bq * Tq)
#define LN_EPS 1e-5f

typedef __attribute__((ext_vector_type(8))) short bf16x8;
typedef __attribute__((ext_vector_type(4))) float f32x4;
typedef __attribute__((ext_vector_type(8))) unsigned short u16x8;

__device__ __forceinline__ unsigned short f2bf(float f) {
    unsigned int u = __float_as_uint(f);
    u += 0x7fffu + ((u >> 16) & 1u);   // round-to-nearest-even
    return (unsigned short)(u >> 16);
}

// ---------------- K0: prep ----------------
__global__ void prep_kernel(const float* __restrict__ pos,
                            const float* __restrict__ ffn_w,
                            float* __restrict__ Pt,            // [C][E]
                            unsigned short* __restrict__ Wb) { // [E][E] bf16
    int i = blockIdx.x * blockDim.x + threadIdx.x;
    if (i < Cq * Eq) {
        int c = i / Eq, e = i % Eq;
        float s = 0.f;
#pragma unroll
        for (int h = 0; h < Hq; ++h) s += pos[(h * Eq + e) * Cq + c];
        Pt[i] = s;
    }
    int nth = blockDim.x * gridDim.x;
    for (int j = i; j < Eq * Eq; j += nth) Wb[j] = f2bf(ffn_w[j]);
}

// ---------------- K1: context ----------------
// one wave per token; 4 tokens per 256-thread block
__global__ __launch_bounds__(256) void ctx_kernel(const int* __restrict__ tokens,
                                                  const float* __restrict__ tbl,
                                                  const float* __restrict__ Pt,
                                                  unsigned short* __restrict__ out1) {
    const int wave = threadIdx.x >> 6;
    const int lane = threadIdx.x & 63;
    const int tt = blockIdx.x * 4 + wave;   // 0..M-1
    const int b = tt >> 11;                 // T = 2048
    const int t = tt & (Tq - 1);

    float x[Cq][8];
    float s[Cq];
#pragma unroll
    for (int c = 0; c < Cq; ++c) {
        const int r = t - (Cq - 1) + c;
        if (r >= 0) {
            const int tok = tokens[(b << 11) + r];
            const float4* row = reinterpret_cast<const float4*>(tbl + (long)tok * Eq + lane * 8);
            float4 v0 = row[0], v1 = row[1];
            x[c][0] = v0.x; x[c][1] = v0.y; x[c][2] = v0.z; x[c][3] = v0.w;
            x[c][4] = v1.x; x[c][5] = v1.y; x[c][6] = v1.z; x[c][7] = v1.w;
        } else {
#pragma unroll
            for (int j = 0; j < 8; ++j) x[c][j] = 0.f;
        }
        const float4* pp = reinterpret_cast<const float4*>(Pt + c * Eq + lane * 8);
        float4 p0 = pp[0], p1 = pp[1];
        s[c] = x[c][0] * p0.x + x[c][1] * p0.y + x[c][2] * p0.z + x[c][3] * p0.w
             + x[c][4] * p1.x + x[c][5] * p1.y + x[c][6] * p1.z + x[c][7] * p1.w;
    }
#pragma unroll
    for (int m = 1; m < 64; m <<= 1) {
        s[0] += __shfl_xor(s[0], m, 64);
        s[1] += __shfl_xor(s[1], m, 64);
        s[2] += __shfl_xor(s[2], m, 64);
    }
    const float inv = 1.f / (Hq * Cq);
    u16x8 o;
#pragma unroll
    for (int j = 0; j < 8; ++j) {
        float v = (s[0] * x[0][j] + s[1] * x[1][j] + s[2] * x[2][j]) * inv;
        o[j] = f2bf(v);
    }
    *reinterpret_cast<u16x8*>(out1 + (long)tt * Eq + lane * 8) = o;
}

// ---------------- K2: FFN GEMM (bf16 MFMA) + bias + LayerNorm + swish ----------------
// grid = M/64 blocks, 512 threads (8 waves). Block computes rows m0..m0+63, full N=512.
// wave w owns cols [64w, 64w+64). MFMA 16x16x32: A row=lane&15, k=8*(lane>>4)+j;
// B col=lane&15, k same; D col=lane&15, row=4*(lane>>4)+i.
__global__ __launch_bounds__(512) void ffn_ln_kernel(const unsigned short* __restrict__ A,
                                                     const unsigned short* __restrict__ Wb,
                                                     const float* __restrict__ bias,
                                                     const float* __restrict__ ln_g,
                                                     const float* __restrict__ ln_b,
                                                     float* __restrict__ out) {
    __shared__ float lds_sum[64][8];
    __shared__ float lds_sq[64][8];
    __shared__ float lds_mu[64];
    __shared__ float lds_rs[64];

    const int wave = threadIdx.x >> 6;
    const int lane = threadIdx.x & 63;
    const int lr = lane & 15;
    const int lg = lane >> 4;
    const int m0 = blockIdx.x << 6;
    const int n0 = wave << 6;

    const short* Ap = reinterpret_cast<const short*>(A) + (long)m0 * Eq;
    const short* Bp = reinterpret_cast<const short*>(Wb) + (long)n0 * Eq;

    f32x4 acc[4][4];
#pragma unroll
    for (int i = 0; i < 4; ++i)
#pragma unroll
        for (int j = 0; j < 4; ++j) acc[i][j] = (f32x4){0.f, 0.f, 0.f, 0.f};

    for (int kb = 0; kb < Eq; kb += 32) {
        const int k = kb + lg * 8;
        bf16x8 af[4], bf[4];
#pragma unroll
        for (int mf = 0; mf < 4; ++mf)
            af[mf] = *reinterpret_cast<const bf16x8*>(Ap + (mf * 16 + lr) * Eq + k);
#pragma unroll
        for (int nf = 0; nf < 4; ++nf)
            bf[nf] = *reinterpret_cast<const bf16x8*>(Bp + (nf * 16 + lr) * Eq + k);
#pragma unroll
        for (int mf = 0; mf < 4; ++mf)
#pragma unroll
            for (int nf = 0; nf < 4; ++nf)
                acc[mf][nf] = __builtin_amdgcn_mfma_f32_16x16x32_bf16(af[mf], bf[nf], acc[mf][nf], 0, 0, 0);
    }

    // bias add + per-row stats (rows this lane holds: mf*16 + lg*4 + i; cols: n0+nf*16+lr)
    float bcol[4];
#pragma unroll
    for (int nf = 0; nf < 4; ++nf) bcol[nf] = bias[n0 + nf * 16 + lr];

#pragma unroll
    for (int mf = 0; mf < 4; ++mf) {
#pragma unroll
        for (int i = 0; i < 4; ++i) {
            float sm = 0.f, sq = 0.f;
#pragma unroll
            for (int nf = 0; nf < 4; ++nf) {
                float v = acc[mf][nf][i] + bcol[nf];
                acc[mf][nf][i] = v;
                sm += v;
                sq += v * v;
            }
            // reduce across the 16 lanes of this lg-group (they share the same rows)
#pragma unroll
            for (int msk = 1; msk < 16; msk <<= 1) {
                sm += __shfl_xor(sm, msk, 64);
                sq += __shfl_xor(sq, msk, 64);
            }
            if (lr == 0) {
                const int row = mf * 16 + lg * 4 + i;
                lds_sum[row][wave] = sm;
                lds_sq[row][wave] = sq;
            }
        }
    }
    __syncthreads();
    if (threadIdx.x < 64) {
        float sm = 0.f, sq = 0.f;
#pragma unroll
        for (int w = 0; w < 8; ++w) { sm += lds_sum[threadIdx.x][w]; sq += lds_sq[threadIdx.x][w]; }
        const float mu = sm * (1.f / Eq);
        const float var = sq * (1.f / Eq) - mu * mu;
        lds_mu[threadIdx.x] = mu;
        lds_rs[threadIdx.x] = rsqrtf(var + LN_EPS);
    }
    __syncthreads();

    float gcol[4], bbcol[4];
#pragma unroll
    for (int nf = 0; nf < 4; ++nf) {
        gcol[nf] = ln_g[n0 + nf * 16 + lr];
        bbcol[nf] = ln_b[n0 + nf * 16 + lr];
    }
#pragma unroll
    for (int mf = 0; mf < 4; ++mf) {
#pragma unroll
        for (int i = 0; i < 4; ++i) {
            const int row = mf * 16 + lg * 4 + i;
            const float mu = lds_mu[row];
            const float rs = lds_rs[row];
#pragma unroll
            for (int nf = 0; nf < 4; ++nf) {
                float v = acc[mf][nf][i];
                float o = (v - mu) * rs * gcol[nf] + bbcol[nf];
                o = o / (1.f + __expf(-o));   // swish
                out[(long)(m0 + row) * Eq + (n0 + nf * 16 + lr)] = o;
            }
        }
    }
}

extern "C" void kernel_launch(void* const* d_in, const int* in_sizes, int n_in,
                              void* d_out, int out_size, void* d_ws, size_t ws_size,
                              hipStream_t stream) {
    const int* tokens = (const int*)d_in[0];
    const float* tbl = (const float*)d_in[1];
    const float* pos = (const float*)d_in[2];
    const float* ffn_w = (const float*)d_in[3];
    const float* ffn_b = (const float*)d_in[4];
    const float* ln_g = (const float*)d_in[5];
    const float* ln_b = (const float*)d_in[6];
    float* out = (float*)d_out;

    char* ws = (char*)d_ws;
    float* Pt = (float*)ws;                                   // 6 KB
    unsigned short* Wb = (unsigned short*)(ws + 8192);        // 512 KB
    unsigned short* out1 = (unsigned short*)(ws + (1 << 20)); // 33.5 MB

    hipLaunchKernelGGL(prep_kernel, dim3(64), dim3(256), 0, stream, pos, ffn_w, Pt, Wb);
    hipLaunchKernelGGL(ctx_kernel, dim3(Mq / 4), dim3(256), 0, stream, tokens, tbl, Pt, out1);
    hipLaunchKernelGGL(ffn_ln_kernel, dim3(Mq / 64), dim3(512), 0, stream, out1, Wb, ffn_b, ln_g, ln_b, out);
}

// Round 2
// 81.707 us; speedup vs baseline: 1.2455x; 1.2455x over previous
//
#include <hip/hip_runtime.h>
#include <hip/hip_bf16.h>

// EmbeddingPredictor: B=16 T=2048 V=32000 E=512 H=4 C=3, f32 in/out.
// R2: K2 gets LDS-staged A (double-buffered, global_load_lds w=16, XOR swizzle).
//  K0 prep:  P[c][e] = sum_h pos[h,e,c];  Wb = bf16(ffn_w)
//  K1 ctx:   per token t: s[c] = dot(x_c, P[:,c]); out1 = sum_c s[c]*x_c /12 -> bf16
//  K2 ffn:   MFMA bf16 GEMM y = out1 @ W^T + b, fused LayerNorm + swish -> f32 out
// ws: Pt @0 (6KB), Wb @8KB (512KB), out1 @1MB (33.5MB).

#define Bq 16
#define Tq 2048
#define Eq 512
#define Cq 3
#define Hq 4
#define Mq (Bq * Tq)
#define LN_EPS 1e-5f

typedef __attribute__((ext_vector_type(8))) short bf16x8;
typedef __attribute__((ext_vector_type(4))) float f32x4;
typedef __attribute__((ext_vector_type(8))) unsigned short u16x8;

__device__ __forceinline__ unsigned short f2bf(float f) {
    unsigned int u = __float_as_uint(f);
    u += 0x7fffu + ((u >> 16) & 1u);   // round-to-nearest-even
    return (unsigned short)(u >> 16);
}

// ---------------- K0: prep ----------------
__global__ void prep_kernel(const float* __restrict__ pos,
                            const float* __restrict__ ffn_w,
                            float* __restrict__ Pt,            // [C][E]
                            unsigned short* __restrict__ Wb) { // [E][E] bf16
    int i = blockIdx.x * blockDim.x + threadIdx.x;
    if (i < Cq * Eq) {
        int c = i / Eq, e = i % Eq;
        float s = 0.f;
#pragma unroll
        for (int h = 0; h < Hq; ++h) s += pos[(h * Eq + e) * Cq + c];
        Pt[i] = s;
    }
    int nth = blockDim.x * gridDim.x;
    for (int j = i; j < Eq * Eq; j += nth) Wb[j] = f2bf(ffn_w[j]);
}

// ---------------- K1: context ----------------
// one wave per token; 4 tokens per 256-thread block
__global__ __launch_bounds__(256) void ctx_kernel(const int* __restrict__ tokens,
                                                  const float* __restrict__ tbl,
                                                  const float* __restrict__ Pt,
                                                  unsigned short* __restrict__ out1) {
    const int wave = threadIdx.x >> 6;
    const int lane = threadIdx.x & 63;
    const int tt = blockIdx.x * 4 + wave;   // 0..M-1
    const int b = tt >> 11;                 // T = 2048
    const int t = tt & (Tq - 1);

    float x[Cq][8];
    float s[Cq];
#pragma unroll
    for (int c = 0; c < Cq; ++c) {
        const int r = t - (Cq - 1) + c;
        if (r >= 0) {
            const int tok = tokens[(b << 11) + r];
            const float4* row = reinterpret_cast<const float4*>(tbl + (long)tok * Eq + lane * 8);
            float4 v0 = row[0], v1 = row[1];
            x[c][0] = v0.x; x[c][1] = v0.y; x[c][2] = v0.z; x[c][3] = v0.w;
            x[c][4] = v1.x; x[c][5] = v1.y; x[c][6] = v1.z; x[c][7] = v1.w;
        } else {
#pragma unroll
            for (int j = 0; j < 8; ++j) x[c][j] = 0.f;
        }
        const float4* pp = reinterpret_cast<const float4*>(Pt + c * Eq + lane * 8);
        float4 p0 = pp[0], p1 = pp[1];
        s[c] = x[c][0] * p0.x + x[c][1] * p0.y + x[c][2] * p0.z + x[c][3] * p0.w
             + x[c][4] * p1.x + x[c][5] * p1.y + x[c][6] * p1.z + x[c][7] * p1.w;
    }
#pragma unroll
    for (int m = 1; m < 64; m <<= 1) {
        s[0] += __shfl_xor(s[0], m, 64);
        s[1] += __shfl_xor(s[1], m, 64);
        s[2] += __shfl_xor(s[2], m, 64);
    }
    const float inv = 1.f / (Hq * Cq);
    u16x8 o;
#pragma unroll
    for (int j = 0; j < 8; ++j) {
        float v = (s[0] * x[0][j] + s[1] * x[1][j] + s[2] * x[2][j]) * inv;
        o[j] = f2bf(v);
    }
    *reinterpret_cast<u16x8*>(out1 + (long)tt * Eq + lane * 8) = o;
}

// ---------------- K2: FFN GEMM (bf16 MFMA) + bias + LayerNorm + swish ----------------
// grid = M/64 blocks, 512 threads (8 waves). Block: rows m0..m0+63, full N=512.
// Wave w owns cols [64w, 64w+64). A tile staged in LDS (double-buffered, BK=64,
// global_load_lds w=16, XOR-swizzle cb ^= (row&7)<<4 on both source and read).
// B direct from global (L2-hot 512KB). MFMA 16x16x32.
__global__ __launch_bounds__(512, 4) void ffn_ln_kernel(const unsigned short* __restrict__ A,
                                                        const unsigned short* __restrict__ Wb,
                                                        const float* __restrict__ bias,
                                                        const float* __restrict__ ln_g,
                                                        const float* __restrict__ ln_b,
                                                        float* __restrict__ out) {
    __shared__ __align__(16) char Atile[2][8192];   // [buf][64 rows][64 cols bf16, swizzled]
    __shared__ float lds_sum[64][8];
    __shared__ float lds_sq[64][8];
    __shared__ float lds_mu[64];
    __shared__ float lds_rs[64];

    const int tid = threadIdx.x;
    const int wave = tid >> 6;
    const int lane = tid & 63;
    const int lr = lane & 15;
    const int lg = lane >> 4;
    const int m0 = blockIdx.x << 6;
    const int n0 = wave << 6;

    const char* Ap = reinterpret_cast<const char*>(A) + (long)m0 * (Eq * 2);
    const short* Bp = reinterpret_cast<const short*>(Wb) + (long)n0 * Eq;

    // staging geometry: thread stages 16B; row = tid>>3, logical col byte
    // cb0 = ((tid&7)^(row&7))<<4 so that LDS (linear in tid) holds the
    // swizzled layout phys = row*128 + (cb ^ ((row&7)<<4)).
    const int r_st = tid >> 3;
    const int cb0 = (((tid & 7) ^ (r_st & 7)) << 4);
    const char* Asrc_base = Ap + r_st * 1024 + cb0;          // + kb*128 bytes per K-block
    char* lds_wave_base[2];
    lds_wave_base[0] = &Atile[0][wave * 1024];
    lds_wave_base[1] = &Atile[1][wave * 1024];

    f32x4 acc[4][4];
#pragma unroll
    for (int i = 0; i < 4; ++i)
#pragma unroll
        for (int j = 0; j < 4; ++j) acc[i][j] = (f32x4){0.f, 0.f, 0.f, 0.f};

    // prologue: stage K-block 0 into buf 0
    __builtin_amdgcn_global_load_lds(
        (const __attribute__((address_space(1))) void*)(Asrc_base),
        (__attribute__((address_space(3))) void*)(lds_wave_base[0]), 16, 0, 0);
    __syncthreads();

    int buf = 0;
#pragma unroll
    for (int kb = 0; kb < 8; ++kb) {               // K-blocks of 64
        if (kb < 7) {
            __builtin_amdgcn_global_load_lds(
                (const __attribute__((address_space(1))) void*)(Asrc_base + (kb + 1) * 128),
                (__attribute__((address_space(3))) void*)(lds_wave_base[buf ^ 1]), 16, 0, 0);
        }
#pragma unroll
        for (int ks = 0; ks < 2; ++ks) {           // two k=32 substeps
            bf16x8 afrag[4], bfrag[4];
#pragma unroll
            for (int mf = 0; mf < 4; ++mf) {
                const int r = mf * 16 + lr;
                const int phys = r * 128 + ((ks * 64 + lg * 16) ^ ((r & 7) << 4));
                afrag[mf] = *reinterpret_cast<const bf16x8*>(&Atile[buf][phys]);
            }
#pragma unroll
            for (int nf = 0; nf < 4; ++nf)
                bfrag[nf] = *reinterpret_cast<const bf16x8*>(Bp + (nf * 16 + lr) * Eq + kb * 64 + ks * 32 + lg * 8);
#pragma unroll
            for (int mf = 0; mf < 4; ++mf)
#pragma unroll
                for (int nf = 0; nf < 4; ++nf)
                    acc[mf][nf] = __builtin_amdgcn_mfma_f32_16x16x32_bf16(afrag[mf], bfrag[nf], acc[mf][nf], 0, 0, 0);
        }
        __syncthreads();
        buf ^= 1;
    }

    // bias add + per-row stats (rows this lane holds: mf*16 + lg*4 + i; cols: n0+nf*16+lr)
    float bcol[4];
#pragma unroll
    for (int nf = 0; nf < 4; ++nf) bcol[nf] = bias[n0 + nf * 16 + lr];

#pragma unroll
    for (int mf = 0; mf < 4; ++mf) {
#pragma unroll
        for (int i = 0; i < 4; ++i) {
            float sm = 0.f, sq = 0.f;
#pragma unroll
            for (int nf = 0; nf < 4; ++nf) {
                float v = acc[mf][nf][i] + bcol[nf];
                acc[mf][nf][i] = v;
                sm += v;
                sq += v * v;
            }
#pragma unroll
            for (int msk = 1; msk < 16; msk <<= 1) {
                sm += __shfl_xor(sm, msk, 64);
                sq += __shfl_xor(sq, msk, 64);
            }
            if (lr == 0) {
                const int row = mf * 16 + lg * 4 + i;
                lds_sum[row][wave] = sm;
                lds_sq[row][wave] = sq;
            }
        }
    }
    __syncthreads();
    if (tid < 64) {
        float sm = 0.f, sq = 0.f;
#pragma unroll
        for (int w = 0; w < 8; ++w) { sm += lds_sum[tid][w]; sq += lds_sq[tid][w]; }
        const float mu = sm * (1.f / Eq);
        const float var = sq * (1.f / Eq) - mu * mu;
        lds_mu[tid] = mu;
        lds_rs[tid] = rsqrtf(var + LN_EPS);
    }
    __syncthreads();

    float gcol[4], bbcol[4];
#pragma unroll
    for (int nf = 0; nf < 4; ++nf) {
        gcol[nf] = ln_g[n0 + nf * 16 + lr];
        bbcol[nf] = ln_b[n0 + nf * 16 + lr];
    }
#pragma unroll
    for (int mf = 0; mf < 4; ++mf) {
#pragma unroll
        for (int i = 0; i < 4; ++i) {
            const int row = mf * 16 + lg * 4 + i;
            const float mu = lds_mu[row];
            const float rs = lds_rs[row];
#pragma unroll
            for (int nf = 0; nf < 4; ++nf) {
                float v = acc[mf][nf][i];
                float o = (v - mu) * rs * gcol[nf] + bbcol[nf];
                o = o / (1.f + __expf(-o));   // swish
                out[(long)(m0 + row) * Eq + (n0 + nf * 16 + lr)] = o;
            }
        }
    }
}

extern "C" void kernel_launch(void* const* d_in, const int* in_sizes, int n_in,
                              void* d_out, int out_size, void* d_ws, size_t ws_size,
                              hipStream_t stream) {
    const int* tokens = (const int*)d_in[0];
    const float* tbl = (const float*)d_in[1];
    const float* pos = (const float*)d_in[2];
    const float* ffn_w = (const float*)d_in[3];
    const float* ffn_b = (const float*)d_in[4];
    const float* ln_g = (const float*)d_in[5];
    const float* ln_b = (const float*)d_in[6];
    float* out = (float*)d_out;

    char* ws = (char*)d_ws;
    float* Pt = (float*)ws;                                   // 6 KB
    unsigned short* Wb = (unsigned short*)(ws + 8192);        // 512 KB
    unsigned short* out1 = (unsigned short*)(ws + (1 << 20)); // 33.5 MB

    hipLaunchKernelGGL(prep_kernel, dim3(64), dim3(256), 0, stream, pos, ffn_w, Pt, Wb);
    hipLaunchKernelGGL(ctx_kernel, dim3(Mq / 4), dim3(256), 0, stream, tokens, tbl, Pt, out1);
    hipLaunchKernelGGL(ffn_ln_kernel, dim3(Mq / 64), dim3(512), 0, stream, out1, Wb, ffn_b, ln_g, ln_b, out);
}

// Round 3
// 74.801 us; speedup vs baseline: 1.3605x; 1.0923x over previous
//
#include <hip/hip_runtime.h>
#include <hip/hip_bf16.h>

// EmbeddingPredictor: B=16 T=2048 V=32000 E=512 H=4 C=3, f32 in/out.
// R3: single fused kernel. Per 64-token block:
//   phase 1 (ctx): each wave owns 8 tokens; loads the 10 distinct embed rows
//     (dedup vs 24), computes s[c]=dot(x_row,P[c]) via shfl-reduce, writes the
//     weighted bf16 combination straight into the swizzled LDS A-tile.
//   phase 2 (ffn): K=512 MFMA loop, NO inner barriers; A from LDS, B from
//     L2-resident Wb. Fused bias + LayerNorm + swish epilogue -> f32 out.
//  K0 prep: P[c][e] = sum_h pos[h,e,c];  Wb = bf16(ffn_w).
// ws: Pt @0 (6KB), Wb @8KB (512KB). out1 intermediate eliminated.

#define Bq 16
#define Tq 2048
#define Eq 512
#define Cq 3
#define Hq 4
#define Mq (Bq * Tq)
#define LN_EPS 1e-5f

typedef __attribute__((ext_vector_type(8))) short bf16x8;
typedef __attribute__((ext_vector_type(4))) float f32x4;
typedef __attribute__((ext_vector_type(8))) unsigned short u16x8;

__device__ __forceinline__ unsigned short f2bf(float f) {
    unsigned int u = __float_as_uint(f);
    u += 0x7fffu + ((u >> 16) & 1u);   // round-to-nearest-even
    return (unsigned short)(u >> 16);
}
__device__ __forceinline__ float bf2f(unsigned short h) {
    return __uint_as_float(((unsigned int)h) << 16);
}

// ---------------- K0: prep ----------------
__global__ void prep_kernel(const float* __restrict__ pos,
                            const float* __restrict__ ffn_w,
                            float* __restrict__ Pt,            // [C][E]
                            unsigned short* __restrict__ Wb) { // [E][E] bf16
    int i = blockIdx.x * blockDim.x + threadIdx.x;
    if (i < Cq * Eq) {
        int c = i / Eq, e = i % Eq;
        float s = 0.f;
#pragma unroll
        for (int h = 0; h < Hq; ++h) s += pos[(h * Eq + e) * Cq + c];
        Pt[i] = s;
    }
    int nth = blockDim.x * gridDim.x;
    for (int j = i; j < Eq * Eq; j += nth) Wb[j] = f2bf(ffn_w[j]);
}

// ---------------- K1: fused ctx + FFN GEMM + bias + LayerNorm + swish ----------------
// grid = M/64 = 512 blocks, 512 threads (8 waves). Block owns rows m0..m0+63.
// Wave w: ctx for tokens m0+8w..m0+8w+7; GEMM cols [64w, 64w+64).
// A tile in LDS, swizzled: phys = row*1024 + (byte_off ^ ((row&7)<<4)).
__global__ __launch_bounds__(512, 4) void fused_kernel(const int* __restrict__ tokens,
                                                       const float* __restrict__ tbl,
                                                       const float* __restrict__ Pt,
                                                       const unsigned short* __restrict__ Wb,
                                                       const float* __restrict__ bias,
                                                       const float* __restrict__ ln_g,
                                                       const float* __restrict__ ln_b,
                                                       float* __restrict__ out) {
    __shared__ __align__(16) unsigned short Atile[64 * 512];   // 64KB, swizzled bf16
    __shared__ float lds_sum[64][8];
    __shared__ float lds_sq[64][8];
    __shared__ float lds_mu[64];
    __shared__ float lds_rs[64];

    const int tid = threadIdx.x;
    const int wave = tid >> 6;
    const int lane = tid & 63;
    const int lr = lane & 15;
    const int lg = lane >> 4;
    const int m0 = blockIdx.x << 6;
    const int b = m0 >> 11;                      // T = 2048
    const int t0w = (m0 & (Tq - 1)) + (wave << 3);

    // ---- phase 1: context -> LDS A tile ----
    // Pt slices for this lane (cols lane*8 .. lane*8+7)
    float4 pA[Cq], pB[Cq];
#pragma unroll
    for (int c = 0; c < Cq; ++c) {
        const float4* pp = reinterpret_cast<const float4*>(Pt + c * Eq + lane * 8);
        pA[c] = pp[0]; pB[c] = pp[1];
    }

    u16x8 xb[10];          // the 10 distinct embed rows, bf16, this lane's slice
    float d[10][Cq];       // partial dots (24 of 30 used)
    const int tbase = b << 11;
#pragma unroll
    for (int li = 0; li < 10; ++li) {
        const int t = t0w - 2 + li;
        float4 v0 = {0.f, 0.f, 0.f, 0.f}, v1 = {0.f, 0.f, 0.f, 0.f};
        if (t >= 0) {
            const int tok = tokens[tbase + t];
            const float4* rp = reinterpret_cast<const float4*>(tbl + (long)tok * Eq + lane * 8);
            v0 = rp[0]; v1 = rp[1];
        }
#pragma unroll
        for (int c = 0; c < Cq; ++c) {
            d[li][c] = v0.x * pA[c].x + v0.y * pA[c].y + v0.z * pA[c].z + v0.w * pA[c].w
                     + v1.x * pB[c].x + v1.y * pB[c].y + v1.z * pB[c].z + v1.w * pB[c].w;
        }
        u16x8 xv;
        xv[0] = f2bf(v0.x); xv[1] = f2bf(v0.y); xv[2] = f2bf(v0.z); xv[3] = f2bf(v0.w);
        xv[4] = f2bf(v1.x); xv[5] = f2bf(v1.y); xv[6] = f2bf(v1.z); xv[7] = f2bf(v1.w);
        xb[li] = xv;
    }
    // wave-reduce the 24 used (li,c) pairs: valid iff 0 <= li-c <= 7
#pragma unroll
    for (int li = 0; li < 10; ++li) {
#pragma unroll
        for (int c = 0; c < Cq; ++c) {
            if (li >= c && li - c <= 7) {
#pragma unroll
                for (int m = 1; m < 64; m <<= 1) d[li][c] += __shfl_xor(d[li][c], m, 64);
            }
        }
    }
    // weighted combination -> bf16 -> swizzled LDS write
    const float inv = 1.f / (Hq * Cq);
#pragma unroll
    for (int j = 0; j < 8; ++j) {
        const float s0 = d[j][0] * inv, s1 = d[j + 1][1] * inv, s2 = d[j + 2][2] * inv;
        u16x8 o;
#pragma unroll
        for (int e = 0; e < 8; ++e) {
            const float a = s0 * bf2f((unsigned short)xb[j][e])
                          + s1 * bf2f((unsigned short)xb[j + 1][e])
                          + s2 * bf2f((unsigned short)xb[j + 2][e]);
            o[e] = f2bf(a);
        }
        const int row = (wave << 3) + j;
        const int phys = row * 1024 + ((lane * 16) ^ ((row & 7) << 4));
        *reinterpret_cast<u16x8*>(reinterpret_cast<char*>(Atile) + phys) = o;
    }
    __syncthreads();

    // ---- phase 2: GEMM, no inner barriers ----
    const int n0 = wave << 6;
    const short* Bp = reinterpret_cast<const short*>(Wb) + (long)n0 * Eq;

    f32x4 acc[4][4];
#pragma unroll
    for (int i = 0; i < 4; ++i)
#pragma unroll
        for (int j = 0; j < 4; ++j) acc[i][j] = (f32x4){0.f, 0.f, 0.f, 0.f};

#pragma unroll
    for (int kb = 0; kb < 8; ++kb) {
#pragma unroll
        for (int ks = 0; ks < 2; ++ks) {
            bf16x8 af[4], bfv[4];
#pragma unroll
            for (int mf = 0; mf < 4; ++mf) {
                const int r = mf * 16 + lr;
                const int phys = r * 1024 + ((kb * 128 + ks * 64 + lg * 16) ^ ((r & 7) << 4));
                af[mf] = *reinterpret_cast<const bf16x8*>(reinterpret_cast<const char*>(Atile) + phys);
            }
#pragma unroll
            for (int nf = 0; nf < 4; ++nf)
                bfv[nf] = *reinterpret_cast<const bf16x8*>(Bp + (nf * 16 + lr) * Eq + kb * 64 + ks * 32 + lg * 8);
#pragma unroll
            for (int mf = 0; mf < 4; ++mf)
#pragma unroll
                for (int nf = 0; nf < 4; ++nf)
                    acc[mf][nf] = __builtin_amdgcn_mfma_f32_16x16x32_bf16(af[mf], bfv[nf], acc[mf][nf], 0, 0, 0);
        }
    }

    // ---- epilogue: bias + LayerNorm + swish ----
    float bcol[4];
#pragma unroll
    for (int nf = 0; nf < 4; ++nf) bcol[nf] = bias[n0 + nf * 16 + lr];

#pragma unroll
    for (int mf = 0; mf < 4; ++mf) {
#pragma unroll
        for (int i = 0; i < 4; ++i) {
            float sm = 0.f, sq = 0.f;
#pragma unroll
            for (int nf = 0; nf < 4; ++nf) {
                float v = acc[mf][nf][i] + bcol[nf];
                acc[mf][nf][i] = v;
                sm += v;
                sq += v * v;
            }
#pragma unroll
            for (int msk = 1; msk < 16; msk <<= 1) {
                sm += __shfl_xor(sm, msk, 64);
                sq += __shfl_xor(sq, msk, 64);
            }
            if (lr == 0) {
                const int row = mf * 16 + lg * 4 + i;
                lds_sum[row][wave] = sm;
                lds_sq[row][wave] = sq;
            }
        }
    }
    __syncthreads();
    if (tid < 64) {
        float sm = 0.f, sq = 0.f;
#pragma unroll
        for (int w = 0; w < 8; ++w) { sm += lds_sum[tid][w]; sq += lds_sq[tid][w]; }
        const float mu = sm * (1.f / Eq);
        const float var = sq * (1.f / Eq) - mu * mu;
        lds_mu[tid] = mu;
        lds_rs[tid] = rsqrtf(var + LN_EPS);
    }
    __syncthreads();

    float gcol[4], bbcol[4];
#pragma unroll
    for (int nf = 0; nf < 4; ++nf) {
        gcol[nf] = ln_g[n0 + nf * 16 + lr];
        bbcol[nf] = ln_b[n0 + nf * 16 + lr];
    }
#pragma unroll
    for (int mf = 0; mf < 4; ++mf) {
#pragma unroll
        for (int i = 0; i < 4; ++i) {
            const int row = mf * 16 + lg * 4 + i;
            const float mu = lds_mu[row];
            const float rs = lds_rs[row];
#pragma unroll
            for (int nf = 0; nf < 4; ++nf) {
                float v = acc[mf][nf][i];
                float o = (v - mu) * rs * gcol[nf] + bbcol[nf];
                o = o / (1.f + __expf(-o));   // swish
                out[(long)(m0 + row) * Eq + (n0 + nf * 16 + lr)] = o;
            }
        }
    }
}

extern "C" void kernel_launch(void* const* d_in, const int* in_sizes, int n_in,
                              void* d_out, int out_size, void* d_ws, size_t ws_size,
                              hipStream_t stream) {
    const int* tokens = (const int*)d_in[0];
    const float* tbl = (const float*)d_in[1];
    const float* pos = (const float*)d_in[2];
    const float* ffn_w = (const float*)d_in[3];
    const float* ffn_b = (const float*)d_in[4];
    const float* ln_g = (const float*)d_in[5];
    const float* ln_b = (const float*)d_in[6];
    float* out = (float*)d_out;

    char* ws = (char*)d_ws;
    float* Pt = (float*)ws;                              // 6 KB
    unsigned short* Wb = (unsigned short*)(ws + 8192);   // 512 KB

    hipLaunchKernelGGL(prep_kernel, dim3(64), dim3(256), 0, stream, pos, ffn_w, Pt, Wb);
    hipLaunchKernelGGL(fused_kernel, dim3(Mq / 64), dim3(512), 0, stream,
                       tokens, tbl, Pt, Wb, ffn_b, ln_g, ln_b, out);
}

// Round 5
// 72.051 us; speedup vs baseline: 1.4124x; 1.0382x over previous
//
#include <hip/hip_runtime.h>
#include <hip/hip_bf16.h>

// EmbeddingPredictor: B=16 T=2048 V=32000 E=512 H=4 C=3, f32 in/out.
// R5: R3 structure (f32 dots, proven absmax 0.031) + register-cap release:
//   __launch_bounds__(512,2): 256-reg budget, no phase-1 spills, x kept in f32 regs
//   explicit 2-deep B-prefetch ring (64 VGPR) issued before the dot/shfl section
//   v_cvt_pk_bf16_f32 for A-tile packing
//  K0 prep: Pt[3][512] f32; Wb = bf16(ffn_w)
// ws: Pt @0 (6KB), Wb @8KB (512KB).

#define Bq 16
#define Tq 2048
#define Eq 512
#define Cq 3
#define Hq 4
#define Mq (Bq * Tq)
#define LN_EPS 1e-5f

typedef __attribute__((ext_vector_type(8))) short bf16x8;
typedef __attribute__((ext_vector_type(4))) float f32x4;

__device__ __forceinline__ unsigned short f2bf(float f) {
    unsigned int u = __float_as_uint(f);
    u += 0x7fffu + ((u >> 16) & 1u);   // round-to-nearest-even
    return (unsigned short)(u >> 16);
}
__device__ __forceinline__ unsigned int cvt_pk_bf16(float lo, float hi) {
    unsigned int r;
    asm("v_cvt_pk_bf16_f32 %0, %1, %2" : "=v"(r) : "v"(lo), "v"(hi));
    return r;   // low16 = bf16(lo), high16 = bf16(hi), RNE
}
// swizzled LDS byte address within a [row][1024B] tile
__device__ __forceinline__ int xaddr(int row, int kbyte) {
    return row * 1024 + (kbyte ^ ((row & 7) << 4));
}

// ---------------- K0: prep ----------------
__global__ void prep_kernel(const float* __restrict__ pos,
                            const float* __restrict__ ffn_w,
                            float* __restrict__ Pt,            // [C][E]
                            unsigned short* __restrict__ Wb) { // [E][E] bf16
    int i = blockIdx.x * blockDim.x + threadIdx.x;
    if (i < Cq * Eq) {
        int c = i / Eq, e = i % Eq;
        float s = 0.f;
#pragma unroll
        for (int h = 0; h < Hq; ++h) s += pos[(h * Eq + e) * Cq + c];
        Pt[i] = s;
    }
    int nth = blockDim.x * gridDim.x;
    for (int j = i; j < Eq * Eq; j += nth) Wb[j] = f2bf(ffn_w[j]);
}

// ---------------- K1: fused ctx + FFN GEMM + bias + LayerNorm + swish ----------------
// grid = M/64 = 512 blocks, 512 threads (8 waves). Block owns tokens m0..m0+63.
// Wave w: ctx for tokens m0+8w..m0+8w+7 (f32, in regs); GEMM cols [64w, 64w+64).
// A tile in LDS, swizzled: phys = row*1024 + (byte ^ ((row&7)<<4)).
__global__ __launch_bounds__(512, 2) void fused_kernel(const int* __restrict__ tokens,
                                                       const float* __restrict__ tbl,
                                                       const float* __restrict__ Pt,
                                                       const unsigned short* __restrict__ Wb,
                                                       const float* __restrict__ bias,
                                                       const float* __restrict__ ln_g,
                                                       const float* __restrict__ ln_b,
                                                       float* __restrict__ out) {
    __shared__ __align__(16) unsigned short Atile[64 * 512];   // 64KB, swizzled bf16
    __shared__ float lds_sum[64][8];
    __shared__ float lds_sq[64][8];
    __shared__ float lds_mu[64];
    __shared__ float lds_rs[64];

    const int tid = threadIdx.x;
    const int wave = tid >> 6;
    const int lane = tid & 63;
    const int lr = lane & 15;
    const int lg = lane >> 4;
    const int m0 = blockIdx.x << 6;
    const int t0w = (m0 & (Tq - 1)) + (wave << 3);
    const int tb = (m0 >> 11) << 11;
    char* Xc = reinterpret_cast<char*>(Atile);

    const int n0 = wave << 6;
    const short* Bp = reinterpret_cast<const short*>(Wb) + (long)n0 * Eq;

    // ---- phase 1a: gather 10 rows in f32 regs ----
    float x[10][8];
#pragma unroll
    for (int li = 0; li < 10; ++li) {
        const int t = t0w - 2 + li;
        float4 v0 = {0.f, 0.f, 0.f, 0.f}, v1 = {0.f, 0.f, 0.f, 0.f};
        if (t >= 0) {
            const int tok = tokens[tb + t];
            const float4* rp = reinterpret_cast<const float4*>(tbl + (long)tok * Eq + lane * 8);
            v0 = rp[0]; v1 = rp[1];
        }
        x[li][0] = v0.x; x[li][1] = v0.y; x[li][2] = v0.z; x[li][3] = v0.w;
        x[li][4] = v1.x; x[li][5] = v1.y; x[li][6] = v1.z; x[li][7] = v1.w;
    }

    // ---- B-prefetch ring: issue kb=0,1 now; latency hides under dots/shfl ----
    bf16x8 br[2][8];   // [ring][ks*4+nf]
#pragma unroll
    for (int ks = 0; ks < 2; ++ks)
#pragma unroll
        for (int nf = 0; nf < 4; ++nf) {
            br[0][ks * 4 + nf] = *reinterpret_cast<const bf16x8*>(Bp + (nf * 16 + lr) * Eq + 0 * 64 + ks * 32 + lg * 8);
            br[1][ks * 4 + nf] = *reinterpret_cast<const bf16x8*>(Bp + (nf * 16 + lr) * Eq + 1 * 64 + ks * 32 + lg * 8);
        }

    // ---- phase 1b: f32 dots + wave reduce ----
    float pv[Cq][8];
#pragma unroll
    for (int c = 0; c < Cq; ++c) {
        const float4* pp = reinterpret_cast<const float4*>(Pt + c * Eq + lane * 8);
        float4 p0 = pp[0], p1 = pp[1];
        pv[c][0] = p0.x; pv[c][1] = p0.y; pv[c][2] = p0.z; pv[c][3] = p0.w;
        pv[c][4] = p1.x; pv[c][5] = p1.y; pv[c][6] = p1.z; pv[c][7] = p1.w;
    }
    float d[10][Cq];
#pragma unroll
    for (int li = 0; li < 10; ++li)
#pragma unroll
        for (int c = 0; c < Cq; ++c)
            if (li >= c && li - c <= 7) {
                float s = 0.f;
#pragma unroll
                for (int e = 0; e < 8; ++e) s += x[li][e] * pv[c][e];
                d[li][c] = s;
            }
#pragma unroll
    for (int li = 0; li < 10; ++li)
#pragma unroll
        for (int c = 0; c < Cq; ++c)
            if (li >= c && li - c <= 7) {
#pragma unroll
                for (int m = 1; m < 64; m <<= 1) d[li][c] += __shfl_xor(d[li][c], m, 64);
            }

    // ---- phase 1c: combination (f32 x) -> cvt_pk -> swizzled LDS A-tile ----
    const float inv = 1.f / (Hq * Cq);
#pragma unroll
    for (int jj = 0; jj < 8; ++jj) {
        const float s0 = d[jj][0] * inv, s1 = d[jj + 1][1] * inv, s2 = d[jj + 2][2] * inv;
        float a[8];
#pragma unroll
        for (int e = 0; e < 8; ++e)
            a[e] = s0 * x[jj][e] + s1 * x[jj + 1][e] + s2 * x[jj + 2][e];
        uint4 o;
        o.x = cvt_pk_bf16(a[0], a[1]);
        o.y = cvt_pk_bf16(a[2], a[3]);
        o.z = cvt_pk_bf16(a[4], a[5]);
        o.w = cvt_pk_bf16(a[6], a[7]);
        const int row = (wave << 3) + jj;
        *reinterpret_cast<uint4*>(Xc + xaddr(row, lane * 16)) = o;
    }
    __syncthreads();

    // ---- phase 2: GEMM, no inner barriers; A from LDS, B via 2-deep ring ----
    f32x4 acc[4][4];
#pragma unroll
    for (int i = 0; i < 4; ++i)
#pragma unroll
        for (int j = 0; j < 4; ++j) acc[i][j] = (f32x4){0.f, 0.f, 0.f, 0.f};

#pragma unroll
    for (int kb = 0; kb < 8; ++kb) {
#pragma unroll
        for (int ks = 0; ks < 2; ++ks) {
            bf16x8 af[4];
#pragma unroll
            for (int mf = 0; mf < 4; ++mf) {
                const int r = mf * 16 + lr;
                af[mf] = *reinterpret_cast<const bf16x8*>(Xc + xaddr(r, kb * 128 + ks * 64 + lg * 16));
            }
#pragma unroll
            for (int mf = 0; mf < 4; ++mf)
#pragma unroll
                for (int nf = 0; nf < 4; ++nf)
                    acc[mf][nf] = __builtin_amdgcn_mfma_f32_16x16x32_bf16(af[mf], br[kb & 1][ks * 4 + nf], acc[mf][nf], 0, 0, 0);
        }
        if (kb < 6) {
#pragma unroll
            for (int ks = 0; ks < 2; ++ks)
#pragma unroll
                for (int nf = 0; nf < 4; ++nf)
                    br[kb & 1][ks * 4 + nf] = *reinterpret_cast<const bf16x8*>(Bp + (nf * 16 + lr) * Eq + (kb + 2) * 64 + ks * 32 + lg * 8);
        }
    }

    // ---- epilogue: bias + LayerNorm + swish ----
    float bcol[4];
#pragma unroll
    for (int nf = 0; nf < 4; ++nf) bcol[nf] = bias[n0 + nf * 16 + lr];

#pragma unroll
    for (int mf = 0; mf < 4; ++mf) {
#pragma unroll
        for (int i = 0; i < 4; ++i) {
            float sm = 0.f, sq = 0.f;
#pragma unroll
            for (int nf = 0; nf < 4; ++nf) {
                float v = acc[mf][nf][i] + bcol[nf];
                acc[mf][nf][i] = v;
                sm += v;
                sq += v * v;
            }
#pragma unroll
            for (int msk = 1; msk < 16; msk <<= 1) {
                sm += __shfl_xor(sm, msk, 64);
                sq += __shfl_xor(sq, msk, 64);
            }
            if (lr == 0) {
                const int row = mf * 16 + lg * 4 + i;
                lds_sum[row][wave] = sm;
                lds_sq[row][wave] = sq;
            }
        }
    }
    __syncthreads();
    if (tid < 64) {
        float sm = 0.f, sq = 0.f;
#pragma unroll
        for (int w = 0; w < 8; ++w) { sm += lds_sum[tid][w]; sq += lds_sq[tid][w]; }
        const float mu = sm * (1.f / Eq);
        const float var = sq * (1.f / Eq) - mu * mu;
        lds_mu[tid] = mu;
        lds_rs[tid] = rsqrtf(var + LN_EPS);
    }
    __syncthreads();

    float gcol[4], bbcol[4];
#pragma unroll
    for (int nf = 0; nf < 4; ++nf) {
        gcol[nf] = ln_g[n0 + nf * 16 + lr];
        bbcol[nf] = ln_b[n0 + nf * 16 + lr];
    }
#pragma unroll
    for (int mf = 0; mf < 4; ++mf) {
#pragma unroll
        for (int i = 0; i < 4; ++i) {
            const int row = mf * 16 + lg * 4 + i;
            const float mu = lds_mu[row];
            const float rs = lds_rs[row];
#pragma unroll
            for (int nf = 0; nf < 4; ++nf) {
                float v = acc[mf][nf][i];
                float o = (v - mu) * rs * gcol[nf] + bbcol[nf];
                o = o / (1.f + __expf(-o));   // swish
                out[(long)(m0 + row) * Eq + (n0 + nf * 16 + lr)] = o;
            }
        }
    }
}

extern "C" void kernel_launch(void* const* d_in, const int* in_sizes, int n_in,
                              void* d_out, int out_size, void* d_ws, size_t ws_size,
                              hipStream_t stream) {
    const int* tokens = (const int*)d_in[0];
    const float* tbl = (const float*)d_in[1];
    const float* pos = (const float*)d_in[2];
    const float* ffn_w = (const float*)d_in[3];
    const float* ffn_b = (const float*)d_in[4];
    const float* ln_g = (const float*)d_in[5];
    const float* ln_b = (const float*)d_in[6];
    float* out = (float*)d_out;

    char* ws = (char*)d_ws;
    float* Pt = (float*)ws;                              // 6 KB
    unsigned short* Wb = (unsigned short*)(ws + 8192);   // 512 KB

    hipLaunchKernelGGL(prep_kernel, dim3(64), dim3(256), 0, stream, pos, ffn_w, Pt, Wb);
    hipLaunchKernelGGL(fused_kernel, dim3(Mq / 64), dim3(512), 0, stream,
                       tokens, tbl, Pt, Wb, ffn_b, ln_g, ln_b, out);
}